// Round 20
// baseline (184.447 us; speedup 1.0000x reference)
//
#include <hip/hip_runtime.h>
#include <hip/hip_bf16.h>

// Problem: B=4, S=2048, D=1024, H=16, hd=64. MHA w/ RoPE, causal, out f32.
// Round 19: R17 config restored (169.9 µs baseline); single change: qkv XCD
// swizzle flipped to n-major-within-XCD (3 B-slices = 768KB pinned per L2,
// A streams sequentially) — targets the 84-132MB L2/L3 re-fetch.

typedef __bf16 bf16x8 __attribute__((ext_vector_type(8)));
typedef float f32x4 __attribute__((ext_vector_type(4)));
typedef unsigned short u16x8 __attribute__((ext_vector_type(8)));

#define DEV static __device__ __forceinline__

DEV unsigned short f2bf(float f) {
  unsigned int u = __builtin_bit_cast(unsigned int, f);
  u += 0x7FFFu + ((u >> 16) & 1u);   // round-to-nearest-even
  return (unsigned short)(u >> 16);
}
DEV float bf2f(unsigned short h) {
  unsigned int u = ((unsigned int)h) << 16;
  return __builtin_bit_cast(float, u);
}
DEV bf16x8 ld_bf8(const unsigned short* p) {
  union { u16x8 u; bf16x8 b; } c;
  c.u = *reinterpret_cast<const u16x8*>(p);
  return c.b;
}
// packed RNE f32x2 -> bf16x2 via HW cvt (lo=a, hi=b)
DEV unsigned int pk2(float a, float b) {
  unsigned int r;
  asm("v_cvt_pk_bf16_f32 %0, %1, %2" : "=v"(r) : "v"(a), "v"(b));
  return r;
}

// global -> LDS direct (16B/lane). dst must be wave-uniform; lane writes dst + lane*16.
DEV void gload_lds16(const unsigned short* src, unsigned short* dst) {
  __builtin_amdgcn_global_load_lds(
      (const __attribute__((address_space(1))) void*)src,
      (__attribute__((address_space(3))) void*)dst, 16, 0, 0);
}

// Stage a 128x64 bf16 tile (row stride ldg elems) into linear LDS [128][64],
// global SOURCE pre-swizzled: LDS[row][c16] = G[row][c16^(row&7)] (rule #21).
DEV void stage_tile(const unsigned short* g, int ldg, unsigned short* lds,
                    int wave, int lane) {
  int rl = lane >> 3;      // row within 8-row issue group
  int c16 = lane & 7;      // 16B chunk in row
#pragma unroll
  for (int i = 0; i < 4; ++i) {
    int row = i * 32 + wave * 8 + rl;
    int sc16 = c16 ^ (row & 7);
    const unsigned short* src = g + (size_t)row * ldg + sc16 * 8;
    unsigned short* dst = lds + (i * 32 + wave * 8) * 64;   // wave-uniform
    gload_lds16(src, dst);
  }
}

// Read one MFMA A/B fragment (8 bf16 along K) from the swizzled tile.
DEV bf16x8 lds_frag(const unsigned short* lds, int row, int c16) {
  return ld_bf8(lds + row * 64 + ((c16 ^ (row & 7)) << 3));
}

// ---------------- f32 -> bf16 convert (vectorized) ----------------
__global__ void k_f32_to_bf16(const float* __restrict__ in,
                              unsigned short* __restrict__ out, int n4) {
  int i = blockIdx.x * blockDim.x + threadIdx.x;
  if (i < n4) {
    float4 v = reinterpret_cast<const float4*>(in)[i];
    uint2 o;
    o.x = pk2(v.x, v.y);
    o.y = pk2(v.z, v.w);
    reinterpret_cast<uint2*>(out)[i] = o;
  }
}

// ---------------- all 4 weight converts in one launch ----------------
__global__ void k_conv_w(const float* __restrict__ Wq, const float* __restrict__ Wk,
                         const float* __restrict__ Wv, const float* __restrict__ Wo,
                         unsigned short* __restrict__ Wb, unsigned short* __restrict__ Wob) {
  int i = blockIdx.x * blockDim.x + threadIdx.x;   // 4 x 262144 f32x4 elements
  int which = i >> 18, j = i & 262143;
  const float* src = (which == 0) ? Wq : (which == 1) ? Wk : (which == 2) ? Wv : Wo;
  unsigned short* dst = (which == 3) ? Wob : Wb + (size_t)which * 1048576;
  float4 v = reinterpret_cast<const float4*>(src)[j];
  uint2 o;
  o.x = pk2(v.x, v.y);
  o.y = pk2(v.z, v.w);
  reinterpret_cast<uint2*>(dst)[j] = o;
}

// ---------------- RoPE cos/sin table (double precision, tiny) ----------------
__global__ void k_rope_table(const int* __restrict__ pos, float* __restrict__ tab) {
  int idx = blockIdx.x * blockDim.x + threadIdx.x; // S*32
  if (idx >= 2048 * 32) return;
  int s = idx >> 5, i = idx & 31;
  double inv = pow(10000.0, -(double)(2 * i) / 64.0);
  double ang = (double)pos[s] * inv;
  tab[idx * 2]     = (float)cos(ang);
  tab[idx * 2 + 1] = (float)sin(ang);
}

// ---------------- QKV GEMM: xb[8192x1024] @ Wcat[3072x1024]^T ----------------
// 128x128 block, 4 waves (2x2), 64x64/wave, LDS-staged K-loop (2-barrier).
// XCD swizzle: n-major within XCD (each XCD owns 3 n-tiles x 64 m-tiles) so
// its 768KB of B stays L2-resident while A streams. Epilogue: Q minimal;
// K RoPE'd scatter; V transposed via LDS stage.
__global__ __launch_bounds__(256) void k_gemm_qkv(
    const unsigned short* __restrict__ A, const unsigned short* __restrict__ W,
    unsigned short* __restrict__ Qh, unsigned short* __restrict__ Kh,
    unsigned short* __restrict__ Vt, const float* __restrict__ tab) {
  const int Kd = 1024, S = 2048;
  __shared__ __align__(16) unsigned short SM[128 * 132];   // 33 KB; K-loop uses first 32KB
  unsigned short* As = SM;
  unsigned short* Bs = SM + 8192;
  // n-major XCD swizzle: 1536 blocks, 8 XCDs x 192 (= 3 n-tiles x 64 m-tiles).
  int id = blockIdx.x;
  int xcd = id & 7, pos = id >> 3;
  int nIdx = xcd * 3 + (pos >> 6);
  int mIdx = pos & 63;
  int m0 = mIdx * 128, n0 = nIdx * 128;
  int wave = threadIdx.x >> 6, lane = threadIdx.x & 63;
  int wm = wave >> 1, wn = wave & 1;
  int lr = lane & 15, lk = lane >> 4;
  const unsigned short* Ag = A + (size_t)m0 * Kd;
  const unsigned short* Wg = W + (size_t)n0 * Kd;
  f32x4 acc[4][4] = {};
  for (int k0 = 0; k0 < Kd; k0 += 64) {
    stage_tile(Ag + k0, Kd, As, wave, lane);
    stage_tile(Wg + k0, Kd, Bs, wave, lane);
    __syncthreads();
#pragma unroll
    for (int ks = 0; ks < 2; ++ks) {
      bf16x8 a[4], b[4];
#pragma unroll
      for (int fm = 0; fm < 4; ++fm) a[fm] = lds_frag(As, wm * 64 + fm * 16 + lr, ks * 4 + lk);
#pragma unroll
      for (int fn = 0; fn < 4; ++fn) b[fn] = lds_frag(Bs, wn * 64 + fn * 16 + lr, ks * 4 + lk);
#pragma unroll
      for (int fm = 0; fm < 4; ++fm)
#pragma unroll
        for (int fn = 0; fn < 4; ++fn)
          acc[fm][fn] = __builtin_amdgcn_mfma_f32_16x16x32_bf16(a[fm], b[fn], acc[fm][fn], 0, 0, 0);
    }
    __syncthreads();
  }

  int t = nIdx >> 3;                // 0=Q, 1=K, 2=V (uniform per block)
  int b = m0 >> 11, s_base = m0 & 2047;
  if (t == 2) {
    // ---- V: stage transposed E[c][s], stride 132, then coalesced stream ----
#pragma unroll
    for (int fm = 0; fm < 4; ++fm) {
      int r0 = wm * 64 + fm * 16 + lk * 4;           // local s of reg 0
#pragma unroll
      for (int fn = 0; fn < 4; ++fn) {
        int c = wn * 64 + fn * 16 + lr;              // local col
        uint2 w;
        w.x = pk2(acc[fm][fn][0], acc[fm][fn][1]);
        w.y = pk2(acc[fm][fn][2], acc[fm][fn][3]);
        *reinterpret_cast<uint2*>(SM + c * 132 + r0) = w;
      }
    }
    __syncthreads();
    int h0 = (nIdx - 16) * 2;
#pragma unroll
    for (int it = 0; it < 16; ++it) {
      int idx2 = it * 256 + threadIdx.x;             // 4096 uint2
      int c = idx2 >> 5, ch = idx2 & 31;             // c row, 8B chunk along s
      int h = h0 + (c >> 6), d = c & 63;
      uint2 w = *reinterpret_cast<const uint2*>(SM + c * 132 + ch * 4);
      *reinterpret_cast<uint2*>(Vt + (((size_t)(b * 16 + h) * 64) + d) * S + s_base + ch * 4) = w;
    }
  } else if (t == 1) {
    // ---- K: RoPE (pairs = adjacent lanes) then minimal scatter ----
    int h0 = (nIdx & 7) * 2;
#pragma unroll
    for (int fm = 0; fm < 4; ++fm) {
      int r0 = wm * 64 + fm * 16 + lk * 4;
#pragma unroll
      for (int fn = 0; fn < 4; ++fn) {
        int c = wn * 64 + fn * 16 + lr;
        int h = h0 + (c >> 6), d = c & 63;
        int ri = d >> 1;
        bool odd = d & 1;
#pragma unroll
        for (int r = 0; r < 4; ++r) {
          int s = s_base + r0 + r;
          float2 cs = reinterpret_cast<const float2*>(tab)[s * 32 + ri];
          float v = acc[fm][fn][r];
          float other = __shfl_xor(v, 1);
          float res = odd ? (other * cs.y + v * cs.x)     // x1*sin + x2*cos
                          : (v * cs.x - other * cs.y);    // x1*cos - x2*sin
          Kh[(((size_t)(b * 16 + h)) * S + s) * 64 + d] = f2bf(res);
        }
      }
    }
  } else {
    // ---- Q: minimal scatter (RoPE applied later in attn's Q load) ----
    int h0 = (nIdx & 7) * 2;
#pragma unroll
    for (int fm = 0; fm < 4; ++fm) {
      int r0 = wm * 64 + fm * 16 + lk * 4;
#pragma unroll
      for (int fn = 0; fn < 4; ++fn) {
        int c = wn * 64 + fn * 16 + lr;
        int h = h0 + (c >> 6), d = c & 63;
#pragma unroll
        for (int r = 0; r < 4; ++r) {
          int s = s_base + r0 + r;
          Qh[(((size_t)(b * 16 + h)) * S + s) * 64 + d] = f2bf(acc[fm][fn][r]);
        }
      }
    }
  }
}

// ---------------- Flash attention (swapped-QK^T, transposed-O, 8 waves) -------
// grid (BH=64, 8). Waves 0-3 -> q-tile 2*yy (32 rows each); waves 4-7 ->
// q-tile 2*yy+1. All 8 waves share one double-buffered K/V staged stream.
// Fixed-shift softmax. Q-rope applied in-register at fragment load (once/wave).
__global__ __launch_bounds__(512) void k_attn(
    const unsigned short* __restrict__ Qh, const unsigned short* __restrict__ Kh,
    const unsigned short* __restrict__ Vt, unsigned short* __restrict__ Obuf,
    const float* __restrict__ tab) {
  const int S = 2048;
  const float KF = 0.18033688f;          // 0.125 * log2(e)
  const float NEGH = -34.624667f;        // -24 * log2(e): fixed softmax shift
  int bh = blockIdx.x;
  int b = bh >> 4, h = bh & 15;
  int wave = threadIdx.x >> 6, lane = threadIdx.x & 63;
  int lr = lane & 15, lk = lane >> 4;
  int yy = (int)gridDim.y - 1 - (int)blockIdx.y;   // heavy pairs dispatch first
  int qt = 2 * yy + (wave >> 2);                   // q-tile of this wave
  int q0 = qt * 128 + (wave & 3) * 32;
  const unsigned short* Qp = Qh + (size_t)bh * S * 64;
  const unsigned short* Kp = Kh + (size_t)bh * S * 64;
  const unsigned short* Vp = Vt + (size_t)bh * 64 * S;

  __shared__ __align__(16) unsigned short Ks[2][64 * 64];   // 16 KB
  __shared__ __align__(16) unsigned short Vs[2][64 * 64];   // 16 KB
  __shared__ __align__(16) unsigned short P_all[8][32][64]; // 32 KB
  char* pw = (char*)&P_all[wave][0][0];

  auto STAGE = [&](int buf, int kv0) {
    int rl = lane >> 3, c16 = lane & 7;
    int row = wave * 8 + rl;
    int sc = (c16 ^ rl) << 3;                 // row&7 == rl
    gload_lds16(Kp + (size_t)(kv0 + row) * 64 + sc, &Ks[buf][wave * 8 * 64]);
    gload_lds16(Vp + (size_t)row * S + kv0 + sc,    &Vs[buf][wave * 8 * 64]);
  };

  // Q fragments with in-register RoPE (pairs are adjacent elems within frag)
  bf16x8 qb[2][2];
#pragma unroll
  for (int mi = 0; mi < 2; ++mi)
#pragma unroll
    for (int ks = 0; ks < 2; ++ks) {
      int s = q0 + mi * 16 + lr;
      int d0 = ks * 32 + lk * 8;
      uint4 v = *reinterpret_cast<const uint4*>(Qp + (size_t)s * 64 + d0);
      const float4* tp = reinterpret_cast<const float4*>(tab + s * 64 + d0);
      float4 t0 = tp[0], t1 = tp[1];
      float cs[4][2] = {{t0.x, t0.y}, {t0.z, t0.w}, {t1.x, t1.y}, {t1.z, t1.w}};
      unsigned int vv[4] = {v.x, v.y, v.z, v.w};
      union { unsigned int u[4]; bf16x8 bv; } r;
#pragma unroll
      for (int pq = 0; pq < 4; ++pq) {
        float x1 = bf2f((unsigned short)(vv[pq] & 0xFFFF));
        float x2 = bf2f((unsigned short)(vv[pq] >> 16));
        r.u[pq] = pk2(x1 * cs[pq][0] - x2 * cs[pq][1], x1 * cs[pq][1] + x2 * cs[pq][0]);
      }
      qb[mi][ks] = r.bv;
    }

  f32x4 acc_o[4][2] = {};                 // O^T: [nf=d-blk][mi]: row=d, col=q
  float l_run[2] = {0.f, 0.f};
  int my_nt = (q0 + 31) / 64 + 1;
  int NT = 2 * (2 * yy + 1) + 2;          // block-max tiles (upper q-tile)

  STAGE(0, 0);
  __syncthreads();                        // drains vmcnt -> buf0 ready

  for (int t = 0; t < NT; ++t) {
    int cur = t & 1;
    if (t + 1 < NT) STAGE(cur ^ 1, (t + 1) * 64);   // async prefetch next tile
    if (t < my_nt) {
      int kv0 = t * 64;
      bf16x8 ka[4][2];
#pragma unroll
      for (int ni = 0; ni < 4; ++ni)
#pragma unroll
        for (int ks = 0; ks < 2; ++ks)
          ka[ni][ks] = lds_frag(&Ks[cur][0], ni * 16 + lr, ks * 4 + lk);
      f32x4 st[4][2] = {};
      __builtin_amdgcn_s_setprio(1);
#pragma unroll
      for (int ni = 0; ni < 4; ++ni)
#pragma unroll
        for (int mi = 0; mi < 2; ++mi) {
          st[ni][mi] = __builtin_amdgcn_mfma_f32_16x16x32_bf16(ka[ni][0], qb[mi][0], st[ni][mi], 0, 0, 0);
          st[ni][mi] = __builtin_amdgcn_mfma_f32_16x16x32_bf16(ka[ni][1], qb[mi][1], st[ni][mi], 0, 0, 0);
        }
      __builtin_amdgcn_s_setprio(0);
      bf16x8 va[4][2];
#pragma unroll
      for (int nf = 0; nf < 4; ++nf)
#pragma unroll
        for (int ks = 0; ks < 2; ++ks)
          va[nf][ks] = lds_frag(&Vs[cur][0], nf * 16 + lr, ks * 4 + lk);

      if (kv0 + 63 > q0) {   // causal mask (wave-uniform branch)
#pragma unroll
        for (int mi = 0; mi < 2; ++mi) {
          int row = q0 + mi * 16 + lr;
#pragma unroll
          for (int ni = 0; ni < 4; ++ni)
#pragma unroll
            for (int r = 0; r < 4; ++r)
              if (kv0 + ni * 16 + lk * 4 + r > row) st[ni][mi][r] = -3e38f;
        }
      }
      // P = exp2(st*KF + NEGH) (fixed shift), HW-packed bf16, swizzled LDS
#pragma unroll
      for (int mi = 0; mi < 2; ++mi) {
        int prow = mi * 16 + lr;
        char* rowp = pw + prow * 128;
        int swz = (lr & 7) << 4;
        float rs = 0.f;
#pragma unroll
        for (int ni = 0; ni < 4; ++ni) {
          float p0 = __builtin_amdgcn_exp2f(fmaf(st[ni][mi][0], KF, NEGH));
          float p1 = __builtin_amdgcn_exp2f(fmaf(st[ni][mi][1], KF, NEGH));
          float p2 = __builtin_amdgcn_exp2f(fmaf(st[ni][mi][2], KF, NEGH));
          float p3 = __builtin_amdgcn_exp2f(fmaf(st[ni][mi][3], KF, NEGH));
          rs += (p0 + p1) + (p2 + p3);
          uint2 w; w.x = pk2(p0, p1); w.y = pk2(p2, p3);
          *reinterpret_cast<uint2*>(rowp + ((ni * 32 + lk * 8) ^ swz)) = w;
        }
        rs += __shfl_xor(rs, 16);
        rs += __shfl_xor(rs, 32);
        l_run[mi] += rs;
      }
      // PV: O^T += V^T · P^T  (P as B operand from swizzled LDS)
      bf16x8 pb[2][2];
#pragma unroll
      for (int mi = 0; mi < 2; ++mi) {
        int prow = mi * 16 + lr;
        int swz = (lr & 7) << 4;
#pragma unroll
        for (int ks = 0; ks < 2; ++ks)
          pb[mi][ks] = ld_bf8((const unsigned short*)(pw + prow * 128 + ((ks * 64 + lk * 16) ^ swz)));
      }
      __builtin_amdgcn_s_setprio(1);
#pragma unroll
      for (int nf = 0; nf < 4; ++nf)
#pragma unroll
        for (int mi = 0; mi < 2; ++mi) {
          acc_o[nf][mi] = __builtin_amdgcn_mfma_f32_16x16x32_bf16(va[nf][0], pb[mi][0], acc_o[nf][mi], 0, 0, 0);
          acc_o[nf][mi] = __builtin_amdgcn_mfma_f32_16x16x32_bf16(va[nf][1], pb[mi][1], acc_o[nf][mi], 0, 0, 0);
        }
      __builtin_amdgcn_s_setprio(0);
    }
    __syncthreads();   // drains vmcnt (stage done) + orders LDS reuse
  }

  // epilogue: O[q][d] = O^T[d][q] / l ; packed 8B stores
#pragma unroll
  for (int mi = 0; mi < 2; ++mi) {
    float inv_l = 1.f / l_run[mi];
    int q = q0 + mi * 16 + lr;
    size_t base = ((size_t)b * S + q) * 1024 + h * 64;
#pragma unroll
    for (int nf = 0; nf < 4; ++nf) {
      uint2 w;
      w.x = pk2(acc_o[nf][mi][0] * inv_l, acc_o[nf][mi][1] * inv_l);
      w.y = pk2(acc_o[nf][mi][2] * inv_l, acc_o[nf][mi][3] * inv_l);
      *reinterpret_cast<uint2*>(Obuf + base + nf * 16 + lk * 4) = w;
    }
  }
}

// ---------------- Output GEMM: Obuf[8192x1024] @ Wo[1024x1024]^T -> f32 ----------------
// XCD-swizzled 1D grid (512 blocks): m-major within XCD.
__global__ __launch_bounds__(256) void k_gemm_out(
    const unsigned short* __restrict__ A, const unsigned short* __restrict__ W,
    float* __restrict__ C) {
  const int Kd = 1024;
  __shared__ __align__(16) unsigned short As[128 * 64];
  __shared__ __align__(16) unsigned short Bs[128 * 64];
  int id = blockIdx.x;
  int xcd = id & 7, pos = id >> 3;
  int nid = xcd * 64 + pos;
  int nIdx = nid & 7, mIdx = nid >> 3;
  int m0 = mIdx * 128, n0 = nIdx * 128;
  int wave = threadIdx.x >> 6, lane = threadIdx.x & 63;
  int wm = wave >> 1, wn = wave & 1;
  int lr = lane & 15, lk = lane >> 4;
  const unsigned short* Ag = A + (size_t)m0 * Kd;
  const unsigned short* Wg = W + (size_t)n0 * Kd;
  f32x4 acc[4][4] = {};
  for (int k0 = 0; k0 < Kd; k0 += 64) {
    stage_tile(Ag + k0, Kd, As, wave, lane);
    stage_tile(Wg + k0, Kd, Bs, wave, lane);
    __syncthreads();
#pragma unroll
    for (int ks = 0; ks < 2; ++ks) {
      bf16x8 a[4], b[4];
#pragma unroll
      for (int fm = 0; fm < 4; ++fm) a[fm] = lds_frag(As, wm * 64 + fm * 16 + lr, ks * 4 + lk);
#pragma unroll
      for (int fn = 0; fn < 4; ++fn) b[fn] = lds_frag(Bs, wn * 64 + fn * 16 + lr, ks * 4 + lk);
#pragma unroll
      for (int fm = 0; fm < 4; ++fm)
#pragma unroll
        for (int fn = 0; fn < 4; ++fn)
          acc[fm][fn] = __builtin_amdgcn_mfma_f32_16x16x32_bf16(a[fm], b[fn], acc[fm][fn], 0, 0, 0);
    }
    __syncthreads();
  }
#pragma unroll
  for (int fm = 0; fm < 4; ++fm)
#pragma unroll
    for (int fn = 0; fn < 4; ++fn)
#pragma unroll
      for (int r = 0; r < 4; ++r)
        C[(size_t)(m0 + wm * 64 + fm * 16 + lk * 4 + r) * 1024 + n0 + wn * 64 + fn * 16 + lr] =
            acc[fm][fn][r];
}

extern "C" void kernel_launch(void* const* d_in, const int* in_sizes, int n_in,
                              void* d_out, int out_size, void* d_ws, size_t ws_size,
                              hipStream_t stream) {
  const float* x  = (const float*)d_in[0];
  const float* Wq = (const float*)d_in[1];
  const float* Wk = (const float*)d_in[2];
  const float* Wv = (const float*)d_in[3];
  const float* Wo = (const float*)d_in[4];
  const int* pos  = (const int*)d_in[5];
  float* out = (float*)d_out;
  char* ws = (char*)d_ws;

  // Workspace layout (bytes):
  unsigned short* xb  = (unsigned short*)(ws);              // 16 MB  x bf16 [8192][1024]
  unsigned short* Wb  = (unsigned short*)(ws + 16777216);   // 6 MB   Wq|Wk|Wv bf16 [3072][1024]
  unsigned short* Wob = (unsigned short*)(ws + 23068672);   // 2 MB   Wo bf16
  unsigned short* Qh  = (unsigned short*)(ws + 25165824);   // 16 MB  [B][H][S][64]
  unsigned short* Kh  = (unsigned short*)(ws + 41943040);   // 16 MB
  unsigned short* Ob  = (unsigned short*)(ws + 58720256);   // 16 MB  attn out bf16
  unsigned short* Vt  = (unsigned short*)(ws + 75497472);   // 16 MB  [B][H][64][S]
  float* tab          = (float*)(ws + 92274688);            // 512 KB cos/sin
  (void)in_sizes; (void)n_in; (void)out_size; (void)ws_size;

  k_f32_to_bf16<<<8192, 256, 0, stream>>>(x, xb, 2097152);
  k_conv_w<<<4096, 256, 0, stream>>>(Wq, Wk, Wv, Wo, Wb, Wob);
  k_rope_table<<<256, 256, 0, stream>>>(pos, tab);

  k_gemm_qkv<<<1536, 256, 0, stream>>>(xb, Wb, Qh, Kh, Vt, tab);
  dim3 ga(64, 8);
  k_attn<<<ga, 512, 0, stream>>>(Qh, Kh, Vt, Ob, tab);
  k_gemm_out<<<512, 256, 0, stream>>>(Ob, Wob, out);
}

// Round 21
// 171.507 us; speedup vs baseline: 1.0754x; 1.0754x over previous
//
#include <hip/hip_runtime.h>
#include <hip/hip_bf16.h>

// Problem: B=4, S=2048, D=1024, H=16, hd=64. MHA w/ RoPE, causal, out f32.
// Round 20: R17 config (best: 169.9 µs) with qkv grid restored to LINEAR 2D
// (x=m, y=n; no manual XCD remap). Swizzle dataset: linear=49.7MB FETCH,
// m-major=84-132MB, n-major=202MB -> default dispatch wins; remaps removed.

typedef __bf16 bf16x8 __attribute__((ext_vector_type(8)));
typedef float f32x4 __attribute__((ext_vector_type(4)));
typedef unsigned short u16x8 __attribute__((ext_vector_type(8)));

#define DEV static __device__ __forceinline__

DEV unsigned short f2bf(float f) {
  unsigned int u = __builtin_bit_cast(unsigned int, f);
  u += 0x7FFFu + ((u >> 16) & 1u);   // round-to-nearest-even
  return (unsigned short)(u >> 16);
}
DEV float bf2f(unsigned short h) {
  unsigned int u = ((unsigned int)h) << 16;
  return __builtin_bit_cast(float, u);
}
DEV bf16x8 ld_bf8(const unsigned short* p) {
  union { u16x8 u; bf16x8 b; } c;
  c.u = *reinterpret_cast<const u16x8*>(p);
  return c.b;
}
// packed RNE f32x2 -> bf16x2 via HW cvt (lo=a, hi=b)
DEV unsigned int pk2(float a, float b) {
  unsigned int r;
  asm("v_cvt_pk_bf16_f32 %0, %1, %2" : "=v"(r) : "v"(a), "v"(b));
  return r;
}

// global -> LDS direct (16B/lane). dst must be wave-uniform; lane writes dst + lane*16.
DEV void gload_lds16(const unsigned short* src, unsigned short* dst) {
  __builtin_amdgcn_global_load_lds(
      (const __attribute__((address_space(1))) void*)src,
      (__attribute__((address_space(3))) void*)dst, 16, 0, 0);
}

// Stage a 128x64 bf16 tile (row stride ldg elems) into linear LDS [128][64],
// global SOURCE pre-swizzled: LDS[row][c16] = G[row][c16^(row&7)] (rule #21).
DEV void stage_tile(const unsigned short* g, int ldg, unsigned short* lds,
                    int wave, int lane) {
  int rl = lane >> 3;      // row within 8-row issue group
  int c16 = lane & 7;      // 16B chunk in row
#pragma unroll
  for (int i = 0; i < 4; ++i) {
    int row = i * 32 + wave * 8 + rl;
    int sc16 = c16 ^ (row & 7);
    const unsigned short* src = g + (size_t)row * ldg + sc16 * 8;
    unsigned short* dst = lds + (i * 32 + wave * 8) * 64;   // wave-uniform
    gload_lds16(src, dst);
  }
}

// Read one MFMA A/B fragment (8 bf16 along K) from the swizzled tile.
DEV bf16x8 lds_frag(const unsigned short* lds, int row, int c16) {
  return ld_bf8(lds + row * 64 + ((c16 ^ (row & 7)) << 3));
}

// ---------------- f32 -> bf16 convert (vectorized) ----------------
__global__ void k_f32_to_bf16(const float* __restrict__ in,
                              unsigned short* __restrict__ out, int n4) {
  int i = blockIdx.x * blockDim.x + threadIdx.x;
  if (i < n4) {
    float4 v = reinterpret_cast<const float4*>(in)[i];
    uint2 o;
    o.x = pk2(v.x, v.y);
    o.y = pk2(v.z, v.w);
    reinterpret_cast<uint2*>(out)[i] = o;
  }
}

// ---------------- all 4 weight converts in one launch ----------------
__global__ void k_conv_w(const float* __restrict__ Wq, const float* __restrict__ Wk,
                         const float* __restrict__ Wv, const float* __restrict__ Wo,
                         unsigned short* __restrict__ Wb, unsigned short* __restrict__ Wob) {
  int i = blockIdx.x * blockDim.x + threadIdx.x;   // 4 x 262144 f32x4 elements
  int which = i >> 18, j = i & 262143;
  const float* src = (which == 0) ? Wq : (which == 1) ? Wk : (which == 2) ? Wv : Wo;
  unsigned short* dst = (which == 3) ? Wob : Wb + (size_t)which * 1048576;
  float4 v = reinterpret_cast<const float4*>(src)[j];
  uint2 o;
  o.x = pk2(v.x, v.y);
  o.y = pk2(v.z, v.w);
  reinterpret_cast<uint2*>(dst)[j] = o;
}

// ---------------- RoPE cos/sin table (double precision, tiny) ----------------
__global__ void k_rope_table(const int* __restrict__ pos, float* __restrict__ tab) {
  int idx = blockIdx.x * blockDim.x + threadIdx.x; // S*32
  if (idx >= 2048 * 32) return;
  int s = idx >> 5, i = idx & 31;
  double inv = pow(10000.0, -(double)(2 * i) / 64.0);
  double ang = (double)pos[s] * inv;
  tab[idx * 2]     = (float)cos(ang);
  tab[idx * 2 + 1] = (float)sin(ang);
}

// ---------------- QKV GEMM: xb[8192x1024] @ Wcat[3072x1024]^T ----------------
// 128x128 block, 4 waves (2x2), 64x64/wave, LDS-staged K-loop (2-barrier).
// Linear 2D grid (x=m, y=n) — measured lowest HBM fetch. Epilogue: Q minimal;
// K RoPE'd scatter; V transposed via LDS stage.
__global__ __launch_bounds__(256) void k_gemm_qkv(
    const unsigned short* __restrict__ A, const unsigned short* __restrict__ W,
    unsigned short* __restrict__ Qh, unsigned short* __restrict__ Kh,
    unsigned short* __restrict__ Vt, const float* __restrict__ tab) {
  const int Kd = 1024, S = 2048;
  __shared__ __align__(16) unsigned short SM[128 * 132];   // 33 KB; K-loop uses first 32KB
  unsigned short* As = SM;
  unsigned short* Bs = SM + 8192;
  int mIdx = blockIdx.x, nIdx = blockIdx.y;
  int m0 = mIdx * 128, n0 = nIdx * 128;
  int wave = threadIdx.x >> 6, lane = threadIdx.x & 63;
  int wm = wave >> 1, wn = wave & 1;
  int lr = lane & 15, lk = lane >> 4;
  const unsigned short* Ag = A + (size_t)m0 * Kd;
  const unsigned short* Wg = W + (size_t)n0 * Kd;
  f32x4 acc[4][4] = {};
  for (int k0 = 0; k0 < Kd; k0 += 64) {
    stage_tile(Ag + k0, Kd, As, wave, lane);
    stage_tile(Wg + k0, Kd, Bs, wave, lane);
    __syncthreads();
#pragma unroll
    for (int ks = 0; ks < 2; ++ks) {
      bf16x8 a[4], b[4];
#pragma unroll
      for (int fm = 0; fm < 4; ++fm) a[fm] = lds_frag(As, wm * 64 + fm * 16 + lr, ks * 4 + lk);
#pragma unroll
      for (int fn = 0; fn < 4; ++fn) b[fn] = lds_frag(Bs, wn * 64 + fn * 16 + lr, ks * 4 + lk);
#pragma unroll
      for (int fm = 0; fm < 4; ++fm)
#pragma unroll
        for (int fn = 0; fn < 4; ++fn)
          acc[fm][fn] = __builtin_amdgcn_mfma_f32_16x16x32_bf16(a[fm], b[fn], acc[fm][fn], 0, 0, 0);
    }
    __syncthreads();
  }

  int t = nIdx >> 3;                // 0=Q, 1=K, 2=V (uniform per block)
  int b = m0 >> 11, s_base = m0 & 2047;
  if (t == 2) {
    // ---- V: stage transposed E[c][s], stride 132, then coalesced stream ----
#pragma unroll
    for (int fm = 0; fm < 4; ++fm) {
      int r0 = wm * 64 + fm * 16 + lk * 4;           // local s of reg 0
#pragma unroll
      for (int fn = 0; fn < 4; ++fn) {
        int c = wn * 64 + fn * 16 + lr;              // local col
        uint2 w;
        w.x = pk2(acc[fm][fn][0], acc[fm][fn][1]);
        w.y = pk2(acc[fm][fn][2], acc[fm][fn][3]);
        *reinterpret_cast<uint2*>(SM + c * 132 + r0) = w;
      }
    }
    __syncthreads();
    int h0 = (nIdx - 16) * 2;
#pragma unroll
    for (int it = 0; it < 16; ++it) {
      int idx2 = it * 256 + threadIdx.x;             // 4096 uint2
      int c = idx2 >> 5, ch = idx2 & 31;             // c row, 8B chunk along s
      int h = h0 + (c >> 6), d = c & 63;
      uint2 w = *reinterpret_cast<const uint2*>(SM + c * 132 + ch * 4);
      *reinterpret_cast<uint2*>(Vt + (((size_t)(b * 16 + h) * 64) + d) * S + s_base + ch * 4) = w;
    }
  } else if (t == 1) {
    // ---- K: RoPE (pairs = adjacent lanes) then minimal scatter ----
    int h0 = (nIdx & 7) * 2;
#pragma unroll
    for (int fm = 0; fm < 4; ++fm) {
      int r0 = wm * 64 + fm * 16 + lk * 4;
#pragma unroll
      for (int fn = 0; fn < 4; ++fn) {
        int c = wn * 64 + fn * 16 + lr;
        int h = h0 + (c >> 6), d = c & 63;
        int ri = d >> 1;
        bool odd = d & 1;
#pragma unroll
        for (int r = 0; r < 4; ++r) {
          int s = s_base + r0 + r;
          float2 cs = reinterpret_cast<const float2*>(tab)[s * 32 + ri];
          float v = acc[fm][fn][r];
          float other = __shfl_xor(v, 1);
          float res = odd ? (other * cs.y + v * cs.x)     // x1*sin + x2*cos
                          : (v * cs.x - other * cs.y);    // x1*cos - x2*sin
          Kh[(((size_t)(b * 16 + h)) * S + s) * 64 + d] = f2bf(res);
        }
      }
    }
  } else {
    // ---- Q: minimal scatter (RoPE applied later in attn's Q load) ----
    int h0 = (nIdx & 7) * 2;
#pragma unroll
    for (int fm = 0; fm < 4; ++fm) {
      int r0 = wm * 64 + fm * 16 + lk * 4;
#pragma unroll
      for (int fn = 0; fn < 4; ++fn) {
        int c = wn * 64 + fn * 16 + lr;
        int h = h0 + (c >> 6), d = c & 63;
#pragma unroll
        for (int r = 0; r < 4; ++r) {
          int s = s_base + r0 + r;
          Qh[(((size_t)(b * 16 + h)) * S + s) * 64 + d] = f2bf(acc[fm][fn][r]);
        }
      }
    }
  }
}

// ---------------- Flash attention (swapped-QK^T, transposed-O, 8 waves) -------
// grid (BH=64, 8). Waves 0-3 -> q-tile 2*yy (32 rows each); waves 4-7 ->
// q-tile 2*yy+1. All 8 waves share one double-buffered K/V staged stream.
// Fixed-shift softmax. Q-rope applied in-register at fragment load (once/wave).
__global__ __launch_bounds__(512) void k_attn(
    const unsigned short* __restrict__ Qh, const unsigned short* __restrict__ Kh,
    const unsigned short* __restrict__ Vt, unsigned short* __restrict__ Obuf,
    const float* __restrict__ tab) {
  const int S = 2048;
  const float KF = 0.18033688f;          // 0.125 * log2(e)
  const float NEGH = -34.624667f;        // -24 * log2(e): fixed softmax shift
  int bh = blockIdx.x;
  int b = bh >> 4, h = bh & 15;
  int wave = threadIdx.x >> 6, lane = threadIdx.x & 63;
  int lr = lane & 15, lk = lane >> 4;
  int yy = (int)gridDim.y - 1 - (int)blockIdx.y;   // heavy pairs dispatch first
  int qt = 2 * yy + (wave >> 2);                   // q-tile of this wave
  int q0 = qt * 128 + (wave & 3) * 32;
  const unsigned short* Qp = Qh + (size_t)bh * S * 64;
  const unsigned short* Kp = Kh + (size_t)bh * S * 64;
  const unsigned short* Vp = Vt + (size_t)bh * 64 * S;

  __shared__ __align__(16) unsigned short Ks[2][64 * 64];   // 16 KB
  __shared__ __align__(16) unsigned short Vs[2][64 * 64];   // 16 KB
  __shared__ __align__(16) unsigned short P_all[8][32][64]; // 32 KB
  char* pw = (char*)&P_all[wave][0][0];

  auto STAGE = [&](int buf, int kv0) {
    int rl = lane >> 3, c16 = lane & 7;
    int row = wave * 8 + rl;
    int sc = (c16 ^ rl) << 3;                 // row&7 == rl
    gload_lds16(Kp + (size_t)(kv0 + row) * 64 + sc, &Ks[buf][wave * 8 * 64]);
    gload_lds16(Vp + (size_t)row * S + kv0 + sc,    &Vs[buf][wave * 8 * 64]);
  };

  // Q fragments with in-register RoPE (pairs are adjacent elems within frag)
  bf16x8 qb[2][2];
#pragma unroll
  for (int mi = 0; mi < 2; ++mi)
#pragma unroll
    for (int ks = 0; ks < 2; ++ks) {
      int s = q0 + mi * 16 + lr;
      int d0 = ks * 32 + lk * 8;
      uint4 v = *reinterpret_cast<const uint4*>(Qp + (size_t)s * 64 + d0);
      const float4* tp = reinterpret_cast<const float4*>(tab + s * 64 + d0);
      float4 t0 = tp[0], t1 = tp[1];
      float cs[4][2] = {{t0.x, t0.y}, {t0.z, t0.w}, {t1.x, t1.y}, {t1.z, t1.w}};
      unsigned int vv[4] = {v.x, v.y, v.z, v.w};
      union { unsigned int u[4]; bf16x8 bv; } r;
#pragma unroll
      for (int pq = 0; pq < 4; ++pq) {
        float x1 = bf2f((unsigned short)(vv[pq] & 0xFFFF));
        float x2 = bf2f((unsigned short)(vv[pq] >> 16));
        r.u[pq] = pk2(x1 * cs[pq][0] - x2 * cs[pq][1], x1 * cs[pq][1] + x2 * cs[pq][0]);
      }
      qb[mi][ks] = r.bv;
    }

  f32x4 acc_o[4][2] = {};                 // O^T: [nf=d-blk][mi]: row=d, col=q
  float l_run[2] = {0.f, 0.f};
  int my_nt = (q0 + 31) / 64 + 1;
  int NT = 2 * (2 * yy + 1) + 2;          // block-max tiles (upper q-tile)

  STAGE(0, 0);
  __syncthreads();                        // drains vmcnt -> buf0 ready

  for (int t = 0; t < NT; ++t) {
    int cur = t & 1;
    if (t + 1 < NT) STAGE(cur ^ 1, (t + 1) * 64);   // async prefetch next tile
    if (t < my_nt) {
      int kv0 = t * 64;
      bf16x8 ka[4][2];
#pragma unroll
      for (int ni = 0; ni < 4; ++ni)
#pragma unroll
        for (int ks = 0; ks < 2; ++ks)
          ka[ni][ks] = lds_frag(&Ks[cur][0], ni * 16 + lr, ks * 4 + lk);
      f32x4 st[4][2] = {};
      __builtin_amdgcn_s_setprio(1);
#pragma unroll
      for (int ni = 0; ni < 4; ++ni)
#pragma unroll
        for (int mi = 0; mi < 2; ++mi) {
          st[ni][mi] = __builtin_amdgcn_mfma_f32_16x16x32_bf16(ka[ni][0], qb[mi][0], st[ni][mi], 0, 0, 0);
          st[ni][mi] = __builtin_amdgcn_mfma_f32_16x16x32_bf16(ka[ni][1], qb[mi][1], st[ni][mi], 0, 0, 0);
        }
      __builtin_amdgcn_s_setprio(0);
      bf16x8 va[4][2];
#pragma unroll
      for (int nf = 0; nf < 4; ++nf)
#pragma unroll
        for (int ks = 0; ks < 2; ++ks)
          va[nf][ks] = lds_frag(&Vs[cur][0], nf * 16 + lr, ks * 4 + lk);

      if (kv0 + 63 > q0) {   // causal mask (wave-uniform branch)
#pragma unroll
        for (int mi = 0; mi < 2; ++mi) {
          int row = q0 + mi * 16 + lr;
#pragma unroll
          for (int ni = 0; ni < 4; ++ni)
#pragma unroll
            for (int r = 0; r < 4; ++r)
              if (kv0 + ni * 16 + lk * 4 + r > row) st[ni][mi][r] = -3e38f;
        }
      }
      // P = exp2(st*KF + NEGH) (fixed shift), HW-packed bf16, swizzled LDS
#pragma unroll
      for (int mi = 0; mi < 2; ++mi) {
        int prow = mi * 16 + lr;
        char* rowp = pw + prow * 128;
        int swz = (lr & 7) << 4;
        float rs = 0.f;
#pragma unroll
        for (int ni = 0; ni < 4; ++ni) {
          float p0 = __builtin_amdgcn_exp2f(fmaf(st[ni][mi][0], KF, NEGH));
          float p1 = __builtin_amdgcn_exp2f(fmaf(st[ni][mi][1], KF, NEGH));
          float p2 = __builtin_amdgcn_exp2f(fmaf(st[ni][mi][2], KF, NEGH));
          float p3 = __builtin_amdgcn_exp2f(fmaf(st[ni][mi][3], KF, NEGH));
          rs += (p0 + p1) + (p2 + p3);
          uint2 w; w.x = pk2(p0, p1); w.y = pk2(p2, p3);
          *reinterpret_cast<uint2*>(rowp + ((ni * 32 + lk * 8) ^ swz)) = w;
        }
        rs += __shfl_xor(rs, 16);
        rs += __shfl_xor(rs, 32);
        l_run[mi] += rs;
      }
      // PV: O^T += V^T · P^T  (P as B operand from swizzled LDS)
      bf16x8 pb[2][2];
#pragma unroll
      for (int mi = 0; mi < 2; ++mi) {
        int prow = mi * 16 + lr;
        int swz = (lr & 7) << 4;
#pragma unroll
        for (int ks = 0; ks < 2; ++ks)
          pb[mi][ks] = ld_bf8((const unsigned short*)(pw + prow * 128 + ((ks * 64 + lk * 16) ^ swz)));
      }
      __builtin_amdgcn_s_setprio(1);
#pragma unroll
      for (int nf = 0; nf < 4; ++nf)
#pragma unroll
        for (int mi = 0; mi < 2; ++mi) {
          acc_o[nf][mi] = __builtin_amdgcn_mfma_f32_16x16x32_bf16(va[nf][0], pb[mi][0], acc_o[nf][mi], 0, 0, 0);
          acc_o[nf][mi] = __builtin_amdgcn_mfma_f32_16x16x32_bf16(va[nf][1], pb[mi][1], acc_o[nf][mi], 0, 0, 0);
        }
      __builtin_amdgcn_s_setprio(0);
    }
    __syncthreads();   // drains vmcnt (stage done) + orders LDS reuse
  }

  // epilogue: O[q][d] = O^T[d][q] / l ; packed 8B stores
#pragma unroll
  for (int mi = 0; mi < 2; ++mi) {
    float inv_l = 1.f / l_run[mi];
    int q = q0 + mi * 16 + lr;
    size_t base = ((size_t)b * S + q) * 1024 + h * 64;
#pragma unroll
    for (int nf = 0; nf < 4; ++nf) {
      uint2 w;
      w.x = pk2(acc_o[nf][mi][0] * inv_l, acc_o[nf][mi][1] * inv_l);
      w.y = pk2(acc_o[nf][mi][2] * inv_l, acc_o[nf][mi][3] * inv_l);
      *reinterpret_cast<uint2*>(Obuf + base + nf * 16 + lk * 4) = w;
    }
  }
}

// ---------------- Output GEMM: Obuf[8192x1024] @ Wo[1024x1024]^T -> f32 ----------------
__global__ __launch_bounds__(256) void k_gemm_out(
    const unsigned short* __restrict__ A, const unsigned short* __restrict__ W,
    float* __restrict__ C) {
  const int Kd = 1024;
  __shared__ __align__(16) unsigned short As[128 * 64];
  __shared__ __align__(16) unsigned short Bs[128 * 64];
  int m0 = blockIdx.x * 128, n0 = blockIdx.y * 128;
  int wave = threadIdx.x >> 6, lane = threadIdx.x & 63;
  int wm = wave >> 1, wn = wave & 1;
  int lr = lane & 15, lk = lane >> 4;
  const unsigned short* Ag = A + (size_t)m0 * Kd;
  const unsigned short* Wg = W + (size_t)n0 * Kd;
  f32x4 acc[4][4] = {};
  for (int k0 = 0; k0 < Kd; k0 += 64) {
    stage_tile(Ag + k0, Kd, As, wave, lane);
    stage_tile(Wg + k0, Kd, Bs, wave, lane);
    __syncthreads();
#pragma unroll
    for (int ks = 0; ks < 2; ++ks) {
      bf16x8 a[4], b[4];
#pragma unroll
      for (int fm = 0; fm < 4; ++fm) a[fm] = lds_frag(As, wm * 64 + fm * 16 + lr, ks * 4 + lk);
#pragma unroll
      for (int fn = 0; fn < 4; ++fn) b[fn] = lds_frag(Bs, wn * 64 + fn * 16 + lr, ks * 4 + lk);
#pragma unroll
      for (int fm = 0; fm < 4; ++fm)
#pragma unroll
        for (int fn = 0; fn < 4; ++fn)
          acc[fm][fn] = __builtin_amdgcn_mfma_f32_16x16x32_bf16(a[fm], b[fn], acc[fm][fn], 0, 0, 0);
    }
    __syncthreads();
  }
#pragma unroll
  for (int fm = 0; fm < 4; ++fm)
#pragma unroll
    for (int fn = 0; fn < 4; ++fn)
#pragma unroll
      for (int r = 0; r < 4; ++r)
        C[(size_t)(m0 + wm * 64 + fm * 16 + lk * 4 + r) * 1024 + n0 + wn * 64 + fn * 16 + lr] =
            acc[fm][fn][r];
}

extern "C" void kernel_launch(void* const* d_in, const int* in_sizes, int n_in,
                              void* d_out, int out_size, void* d_ws, size_t ws_size,
                              hipStream_t stream) {
  const float* x  = (const float*)d_in[0];
  const float* Wq = (const float*)d_in[1];
  const float* Wk = (const float*)d_in[2];
  const float* Wv = (const float*)d_in[3];
  const float* Wo = (const float*)d_in[4];
  const int* pos  = (const int*)d_in[5];
  float* out = (float*)d_out;
  char* ws = (char*)d_ws;

  // Workspace layout (bytes):
  unsigned short* xb  = (unsigned short*)(ws);              // 16 MB  x bf16 [8192][1024]
  unsigned short* Wb  = (unsigned short*)(ws + 16777216);   // 6 MB   Wq|Wk|Wv bf16 [3072][1024]
  unsigned short* Wob = (unsigned short*)(ws + 23068672);   // 2 MB   Wo bf16
  unsigned short* Qh  = (unsigned short*)(ws + 25165824);   // 16 MB  [B][H][S][64]
  unsigned short* Kh  = (unsigned short*)(ws + 41943040);   // 16 MB
  unsigned short* Ob  = (unsigned short*)(ws + 58720256);   // 16 MB  attn out bf16
  unsigned short* Vt  = (unsigned short*)(ws + 75497472);   // 16 MB  [B][H][64][S]
  float* tab          = (float*)(ws + 92274688);            // 512 KB cos/sin
  (void)in_sizes; (void)n_in; (void)out_size; (void)ws_size;

  k_f32_to_bf16<<<8192, 256, 0, stream>>>(x, xb, 2097152);
  k_conv_w<<<4096, 256, 0, stream>>>(Wq, Wk, Wv, Wo, Wb, Wob);
  k_rope_table<<<256, 256, 0, stream>>>(pos, tab);

  dim3 g1(64, 24);
  k_gemm_qkv<<<g1, 256, 0, stream>>>(xb, Wb, Qh, Kh, Vt, tab);
  dim3 ga(64, 8);
  k_attn<<<ga, 512, 0, stream>>>(Qh, Kh, Vt, Ob, tab);
  dim3 g2(64, 8);
  k_gemm_out<<<g2, 256, 0, stream>>>(Ob, Wob, out);
}

// Round 22
// 169.790 us; speedup vs baseline: 1.0863x; 1.0101x over previous
//
#include <hip/hip_runtime.h>
#include <hip/hip_bf16.h>

// Problem: B=4, S=2048, D=1024, H=16, hd=64. MHA w/ RoPE, causal, out f32.
// Round 21: R20 config (fixed-shift softmax, 8-wave attn, Q-rope in-reg,
// K-rope in qkv epilogue, V^T LDS-coalesced, linear grids) + the three prep
// kernels merged into one launch (k_prep, proven in R18).

typedef __bf16 bf16x8 __attribute__((ext_vector_type(8)));
typedef float f32x4 __attribute__((ext_vector_type(4)));
typedef unsigned short u16x8 __attribute__((ext_vector_type(8)));

#define DEV static __device__ __forceinline__

DEV unsigned short f2bf(float f) {
  unsigned int u = __builtin_bit_cast(unsigned int, f);
  u += 0x7FFFu + ((u >> 16) & 1u);   // round-to-nearest-even
  return (unsigned short)(u >> 16);
}
DEV float bf2f(unsigned short h) {
  unsigned int u = ((unsigned int)h) << 16;
  return __builtin_bit_cast(float, u);
}
DEV bf16x8 ld_bf8(const unsigned short* p) {
  union { u16x8 u; bf16x8 b; } c;
  c.u = *reinterpret_cast<const u16x8*>(p);
  return c.b;
}
// packed RNE f32x2 -> bf16x2 via HW cvt (lo=a, hi=b)
DEV unsigned int pk2(float a, float b) {
  unsigned int r;
  asm("v_cvt_pk_bf16_f32 %0, %1, %2" : "=v"(r) : "v"(a), "v"(b));
  return r;
}

// global -> LDS direct (16B/lane). dst must be wave-uniform; lane writes dst + lane*16.
DEV void gload_lds16(const unsigned short* src, unsigned short* dst) {
  __builtin_amdgcn_global_load_lds(
      (const __attribute__((address_space(1))) void*)src,
      (__attribute__((address_space(3))) void*)dst, 16, 0, 0);
}

// Stage a 128x64 bf16 tile (row stride ldg elems) into linear LDS [128][64],
// global SOURCE pre-swizzled: LDS[row][c16] = G[row][c16^(row&7)] (rule #21).
DEV void stage_tile(const unsigned short* g, int ldg, unsigned short* lds,
                    int wave, int lane) {
  int rl = lane >> 3;      // row within 8-row issue group
  int c16 = lane & 7;      // 16B chunk in row
#pragma unroll
  for (int i = 0; i < 4; ++i) {
    int row = i * 32 + wave * 8 + rl;
    int sc16 = c16 ^ (row & 7);
    const unsigned short* src = g + (size_t)row * ldg + sc16 * 8;
    unsigned short* dst = lds + (i * 32 + wave * 8) * 64;   // wave-uniform
    gload_lds16(src, dst);
  }
}

// Read one MFMA A/B fragment (8 bf16 along K) from the swizzled tile.
DEV bf16x8 lds_frag(const unsigned short* lds, int row, int c16) {
  return ld_bf8(lds + row * 64 + ((c16 ^ (row & 7)) << 3));
}

// ---------------- merged prep: x/W converts + rope table ----------------
__global__ __launch_bounds__(256) void k_prep(
    const float* __restrict__ x, const float* __restrict__ Wq,
    const float* __restrict__ Wk, const float* __restrict__ Wv,
    const float* __restrict__ Wo, const int* __restrict__ pos,
    unsigned short* __restrict__ xb, unsigned short* __restrict__ Wb,
    unsigned short* __restrict__ Wob, float* __restrict__ tab) {
  int bid = blockIdx.x;
  if (bid < 8192) {                     // x convert: 2097152 f32x4
    int i = bid * 256 + threadIdx.x;
    float4 v = reinterpret_cast<const float4*>(x)[i];
    uint2 o; o.x = pk2(v.x, v.y); o.y = pk2(v.z, v.w);
    reinterpret_cast<uint2*>(xb)[i] = o;
  } else if (bid < 12288) {             // weight converts: 4 x 262144 f32x4
    int i = (bid - 8192) * 256 + threadIdx.x;
    int which = i >> 18, j = i & 262143;
    const float* src = (which == 0) ? Wq : (which == 1) ? Wk : (which == 2) ? Wv : Wo;
    unsigned short* dst = (which == 3) ? Wob : Wb + (size_t)which * 1048576;
    float4 v = reinterpret_cast<const float4*>(src)[j];
    uint2 o; o.x = pk2(v.x, v.y); o.y = pk2(v.z, v.w);
    reinterpret_cast<uint2*>(dst)[j] = o;
  } else {                              // rope table: 65536 entries
    int idx = (bid - 12288) * 256 + threadIdx.x;
    int s = idx >> 5, i = idx & 31;
    double inv = pow(10000.0, -(double)(2 * i) / 64.0);
    double ang = (double)pos[s] * inv;
    tab[idx * 2]     = (float)cos(ang);
    tab[idx * 2 + 1] = (float)sin(ang);
  }
}

// ---------------- QKV GEMM: xb[8192x1024] @ Wcat[3072x1024]^T ----------------
// 128x128 block, 4 waves (2x2), 64x64/wave, LDS-staged K-loop (2-barrier).
// Linear 2D grid (x=m, y=n) — measured lowest HBM fetch. Epilogue: Q minimal;
// K RoPE'd scatter; V transposed via LDS stage.
__global__ __launch_bounds__(256) void k_gemm_qkv(
    const unsigned short* __restrict__ A, const unsigned short* __restrict__ W,
    unsigned short* __restrict__ Qh, unsigned short* __restrict__ Kh,
    unsigned short* __restrict__ Vt, const float* __restrict__ tab) {
  const int Kd = 1024, S = 2048;
  __shared__ __align__(16) unsigned short SM[128 * 132];   // 33 KB; K-loop uses first 32KB
  unsigned short* As = SM;
  unsigned short* Bs = SM + 8192;
  int mIdx = blockIdx.x, nIdx = blockIdx.y;
  int m0 = mIdx * 128, n0 = nIdx * 128;
  int wave = threadIdx.x >> 6, lane = threadIdx.x & 63;
  int wm = wave >> 1, wn = wave & 1;
  int lr = lane & 15, lk = lane >> 4;
  const unsigned short* Ag = A + (size_t)m0 * Kd;
  const unsigned short* Wg = W + (size_t)n0 * Kd;
  f32x4 acc[4][4] = {};
  for (int k0 = 0; k0 < Kd; k0 += 64) {
    stage_tile(Ag + k0, Kd, As, wave, lane);
    stage_tile(Wg + k0, Kd, Bs, wave, lane);
    __syncthreads();
#pragma unroll
    for (int ks = 0; ks < 2; ++ks) {
      bf16x8 a[4], b[4];
#pragma unroll
      for (int fm = 0; fm < 4; ++fm) a[fm] = lds_frag(As, wm * 64 + fm * 16 + lr, ks * 4 + lk);
#pragma unroll
      for (int fn = 0; fn < 4; ++fn) b[fn] = lds_frag(Bs, wn * 64 + fn * 16 + lr, ks * 4 + lk);
#pragma unroll
      for (int fm = 0; fm < 4; ++fm)
#pragma unroll
        for (int fn = 0; fn < 4; ++fn)
          acc[fm][fn] = __builtin_amdgcn_mfma_f32_16x16x32_bf16(a[fm], b[fn], acc[fm][fn], 0, 0, 0);
    }
    __syncthreads();
  }

  int t = nIdx >> 3;                // 0=Q, 1=K, 2=V (uniform per block)
  int b = m0 >> 11, s_base = m0 & 2047;
  if (t == 2) {
    // ---- V: stage transposed E[c][s], stride 132, then coalesced stream ----
#pragma unroll
    for (int fm = 0; fm < 4; ++fm) {
      int r0 = wm * 64 + fm * 16 + lk * 4;           // local s of reg 0
#pragma unroll
      for (int fn = 0; fn < 4; ++fn) {
        int c = wn * 64 + fn * 16 + lr;              // local col
        uint2 w;
        w.x = pk2(acc[fm][fn][0], acc[fm][fn][1]);
        w.y = pk2(acc[fm][fn][2], acc[fm][fn][3]);
        *reinterpret_cast<uint2*>(SM + c * 132 + r0) = w;
      }
    }
    __syncthreads();
    int h0 = (nIdx - 16) * 2;
#pragma unroll
    for (int it = 0; it < 16; ++it) {
      int idx2 = it * 256 + threadIdx.x;             // 4096 uint2
      int c = idx2 >> 5, ch = idx2 & 31;             // c row, 8B chunk along s
      int h = h0 + (c >> 6), d = c & 63;
      uint2 w = *reinterpret_cast<const uint2*>(SM + c * 132 + ch * 4);
      *reinterpret_cast<uint2*>(Vt + (((size_t)(b * 16 + h) * 64) + d) * S + s_base + ch * 4) = w;
    }
  } else if (t == 1) {
    // ---- K: RoPE (pairs = adjacent lanes) then minimal scatter ----
    int h0 = (nIdx & 7) * 2;
#pragma unroll
    for (int fm = 0; fm < 4; ++fm) {
      int r0 = wm * 64 + fm * 16 + lk * 4;
#pragma unroll
      for (int fn = 0; fn < 4; ++fn) {
        int c = wn * 64 + fn * 16 + lr;
        int h = h0 + (c >> 6), d = c & 63;
        int ri = d >> 1;
        bool odd = d & 1;
#pragma unroll
        for (int r = 0; r < 4; ++r) {
          int s = s_base + r0 + r;
          float2 cs = reinterpret_cast<const float2*>(tab)[s * 32 + ri];
          float v = acc[fm][fn][r];
          float other = __shfl_xor(v, 1);
          float res = odd ? (other * cs.y + v * cs.x)     // x1*sin + x2*cos
                          : (v * cs.x - other * cs.y);    // x1*cos - x2*sin
          Kh[(((size_t)(b * 16 + h)) * S + s) * 64 + d] = f2bf(res);
        }
      }
    }
  } else {
    // ---- Q: minimal scatter (RoPE applied later in attn's Q load) ----
    int h0 = (nIdx & 7) * 2;
#pragma unroll
    for (int fm = 0; fm < 4; ++fm) {
      int r0 = wm * 64 + fm * 16 + lk * 4;
#pragma unroll
      for (int fn = 0; fn < 4; ++fn) {
        int c = wn * 64 + fn * 16 + lr;
        int h = h0 + (c >> 6), d = c & 63;
#pragma unroll
        for (int r = 0; r < 4; ++r) {
          int s = s_base + r0 + r;
          Qh[(((size_t)(b * 16 + h)) * S + s) * 64 + d] = f2bf(acc[fm][fn][r]);
        }
      }
    }
  }
}

// ---------------- Flash attention (swapped-QK^T, transposed-O, 8 waves) -------
// grid (BH=64, 8). Waves 0-3 -> q-tile 2*yy (32 rows each); waves 4-7 ->
// q-tile 2*yy+1. All 8 waves share one double-buffered K/V staged stream.
// Fixed-shift softmax. Q-rope applied in-register at fragment load (once/wave).
__global__ __launch_bounds__(512) void k_attn(
    const unsigned short* __restrict__ Qh, const unsigned short* __restrict__ Kh,
    const unsigned short* __restrict__ Vt, unsigned short* __restrict__ Obuf,
    const float* __restrict__ tab) {
  const int S = 2048;
  const float KF = 0.18033688f;          // 0.125 * log2(e)
  const float NEGH = -34.624667f;        // -24 * log2(e): fixed softmax shift
  int bh = blockIdx.x;
  int b = bh >> 4, h = bh & 15;
  int wave = threadIdx.x >> 6, lane = threadIdx.x & 63;
  int lr = lane & 15, lk = lane >> 4;
  int yy = (int)gridDim.y - 1 - (int)blockIdx.y;   // heavy pairs dispatch first
  int qt = 2 * yy + (wave >> 2);                   // q-tile of this wave
  int q0 = qt * 128 + (wave & 3) * 32;
  const unsigned short* Qp = Qh + (size_t)bh * S * 64;
  const unsigned short* Kp = Kh + (size_t)bh * S * 64;
  const unsigned short* Vp = Vt + (size_t)bh * 64 * S;

  __shared__ __align__(16) unsigned short Ks[2][64 * 64];   // 16 KB
  __shared__ __align__(16) unsigned short Vs[2][64 * 64];   // 16 KB
  __shared__ __align__(16) unsigned short P_all[8][32][64]; // 32 KB
  char* pw = (char*)&P_all[wave][0][0];

  auto STAGE = [&](int buf, int kv0) {
    int rl = lane >> 3, c16 = lane & 7;
    int row = wave * 8 + rl;
    int sc = (c16 ^ rl) << 3;                 // row&7 == rl
    gload_lds16(Kp + (size_t)(kv0 + row) * 64 + sc, &Ks[buf][wave * 8 * 64]);
    gload_lds16(Vp + (size_t)row * S + kv0 + sc,    &Vs[buf][wave * 8 * 64]);
  };

  // Q fragments with in-register RoPE (pairs are adjacent elems within frag)
  bf16x8 qb[2][2];
#pragma unroll
  for (int mi = 0; mi < 2; ++mi)
#pragma unroll
    for (int ks = 0; ks < 2; ++ks) {
      int s = q0 + mi * 16 + lr;
      int d0 = ks * 32 + lk * 8;
      uint4 v = *reinterpret_cast<const uint4*>(Qp + (size_t)s * 64 + d0);
      const float4* tp = reinterpret_cast<const float4*>(tab + s * 64 + d0);
      float4 t0 = tp[0], t1 = tp[1];
      float cs[4][2] = {{t0.x, t0.y}, {t0.z, t0.w}, {t1.x, t1.y}, {t1.z, t1.w}};
      unsigned int vv[4] = {v.x, v.y, v.z, v.w};
      union { unsigned int u[4]; bf16x8 bv; } r;
#pragma unroll
      for (int pq = 0; pq < 4; ++pq) {
        float x1 = bf2f((unsigned short)(vv[pq] & 0xFFFF));
        float x2 = bf2f((unsigned short)(vv[pq] >> 16));
        r.u[pq] = pk2(x1 * cs[pq][0] - x2 * cs[pq][1], x1 * cs[pq][1] + x2 * cs[pq][0]);
      }
      qb[mi][ks] = r.bv;
    }

  f32x4 acc_o[4][2] = {};                 // O^T: [nf=d-blk][mi]: row=d, col=q
  float l_run[2] = {0.f, 0.f};
  int my_nt = (q0 + 31) / 64 + 1;
  int NT = 2 * (2 * yy + 1) + 2;          // block-max tiles (upper q-tile)

  STAGE(0, 0);
  __syncthreads();                        // drains vmcnt -> buf0 ready

  for (int t = 0; t < NT; ++t) {
    int cur = t & 1;
    if (t + 1 < NT) STAGE(cur ^ 1, (t + 1) * 64);   // async prefetch next tile
    if (t < my_nt) {
      int kv0 = t * 64;
      bf16x8 ka[4][2];
#pragma unroll
      for (int ni = 0; ni < 4; ++ni)
#pragma unroll
        for (int ks = 0; ks < 2; ++ks)
          ka[ni][ks] = lds_frag(&Ks[cur][0], ni * 16 + lr, ks * 4 + lk);
      f32x4 st[4][2] = {};
      __builtin_amdgcn_s_setprio(1);
#pragma unroll
      for (int ni = 0; ni < 4; ++ni)
#pragma unroll
        for (int mi = 0; mi < 2; ++mi) {
          st[ni][mi] = __builtin_amdgcn_mfma_f32_16x16x32_bf16(ka[ni][0], qb[mi][0], st[ni][mi], 0, 0, 0);
          st[ni][mi] = __builtin_amdgcn_mfma_f32_16x16x32_bf16(ka[ni][1], qb[mi][1], st[ni][mi], 0, 0, 0);
        }
      __builtin_amdgcn_s_setprio(0);
      bf16x8 va[4][2];
#pragma unroll
      for (int nf = 0; nf < 4; ++nf)
#pragma unroll
        for (int ks = 0; ks < 2; ++ks)
          va[nf][ks] = lds_frag(&Vs[cur][0], nf * 16 + lr, ks * 4 + lk);

      if (kv0 + 63 > q0) {   // causal mask (wave-uniform branch)
#pragma unroll
        for (int mi = 0; mi < 2; ++mi) {
          int row = q0 + mi * 16 + lr;
#pragma unroll
          for (int ni = 0; ni < 4; ++ni)
#pragma unroll
            for (int r = 0; r < 4; ++r)
              if (kv0 + ni * 16 + lk * 4 + r > row) st[ni][mi][r] = -3e38f;
        }
      }
      // P = exp2(st*KF + NEGH) (fixed shift), HW-packed bf16, swizzled LDS
#pragma unroll
      for (int mi = 0; mi < 2; ++mi) {
        int prow = mi * 16 + lr;
        char* rowp = pw + prow * 128;
        int swz = (lr & 7) << 4;
        float rs = 0.f;
#pragma unroll
        for (int ni = 0; ni < 4; ++ni) {
          float p0 = __builtin_amdgcn_exp2f(fmaf(st[ni][mi][0], KF, NEGH));
          float p1 = __builtin_amdgcn_exp2f(fmaf(st[ni][mi][1], KF, NEGH));
          float p2 = __builtin_amdgcn_exp2f(fmaf(st[ni][mi][2], KF, NEGH));
          float p3 = __builtin_amdgcn_exp2f(fmaf(st[ni][mi][3], KF, NEGH));
          rs += (p0 + p1) + (p2 + p3);
          uint2 w; w.x = pk2(p0, p1); w.y = pk2(p2, p3);
          *reinterpret_cast<uint2*>(rowp + ((ni * 32 + lk * 8) ^ swz)) = w;
        }
        rs += __shfl_xor(rs, 16);
        rs += __shfl_xor(rs, 32);
        l_run[mi] += rs;
      }
      // PV: O^T += V^T · P^T  (P as B operand from swizzled LDS)
      bf16x8 pb[2][2];
#pragma unroll
      for (int mi = 0; mi < 2; ++mi) {
        int prow = mi * 16 + lr;
        int swz = (lr & 7) << 4;
#pragma unroll
        for (int ks = 0; ks < 2; ++ks)
          pb[mi][ks] = ld_bf8((const unsigned short*)(pw + prow * 128 + ((ks * 64 + lk * 16) ^ swz)));
      }
      __builtin_amdgcn_s_setprio(1);
#pragma unroll
      for (int nf = 0; nf < 4; ++nf)
#pragma unroll
        for (int mi = 0; mi < 2; ++mi) {
          acc_o[nf][mi] = __builtin_amdgcn_mfma_f32_16x16x32_bf16(va[nf][0], pb[mi][0], acc_o[nf][mi], 0, 0, 0);
          acc_o[nf][mi] = __builtin_amdgcn_mfma_f32_16x16x32_bf16(va[nf][1], pb[mi][1], acc_o[nf][mi], 0, 0, 0);
        }
      __builtin_amdgcn_s_setprio(0);
    }
    __syncthreads();   // drains vmcnt (stage done) + orders LDS reuse
  }

  // epilogue: O[q][d] = O^T[d][q] / l ; packed 8B stores
#pragma unroll
  for (int mi = 0; mi < 2; ++mi) {
    float inv_l = 1.f / l_run[mi];
    int q = q0 + mi * 16 + lr;
    size_t base = ((size_t)b * S + q) * 1024 + h * 64;
#pragma unroll
    for (int nf = 0; nf < 4; ++nf) {
      uint2 w;
      w.x = pk2(acc_o[nf][mi][0] * inv_l, acc_o[nf][mi][1] * inv_l);
      w.y = pk2(acc_o[nf][mi][2] * inv_l, acc_o[nf][mi][3] * inv_l);
      *reinterpret_cast<uint2*>(Obuf + base + nf * 16 + lk * 4) = w;
    }
  }
}

// ---------------- Output GEMM: Obuf[8192x1024] @ Wo[1024x1024]^T -> f32 ----------------
__global__ __launch_bounds__(256) void k_gemm_out(
    const unsigned short* __restrict__ A, const unsigned short* __restrict__ W,
    float* __restrict__ C) {
  const int Kd = 1024;
  __shared__ __align__(16) unsigned short As[128 * 64];
  __shared__ __align__(16) unsigned short Bs[128 * 64];
  int m0 = blockIdx.x * 128, n0 = blockIdx.y * 128;
  int wave = threadIdx.x >> 6, lane = threadIdx.x & 63;
  int wm = wave >> 1, wn = wave & 1;
  int lr = lane & 15, lk = lane >> 4;
  const unsigned short* Ag = A + (size_t)m0 * Kd;
  const unsigned short* Wg = W + (size_t)n0 * Kd;
  f32x4 acc[4][4] = {};
  for (int k0 = 0; k0 < Kd; k0 += 64) {
    stage_tile(Ag + k0, Kd, As, wave, lane);
    stage_tile(Wg + k0, Kd, Bs, wave, lane);
    __syncthreads();
#pragma unroll
    for (int ks = 0; ks < 2; ++ks) {
      bf16x8 a[4], b[4];
#pragma unroll
      for (int fm = 0; fm < 4; ++fm) a[fm] = lds_frag(As, wm * 64 + fm * 16 + lr, ks * 4 + lk);
#pragma unroll
      for (int fn = 0; fn < 4; ++fn) b[fn] = lds_frag(Bs, wn * 64 + fn * 16 + lr, ks * 4 + lk);
#pragma unroll
      for (int fm = 0; fm < 4; ++fm)
#pragma unroll
        for (int fn = 0; fn < 4; ++fn)
          acc[fm][fn] = __builtin_amdgcn_mfma_f32_16x16x32_bf16(a[fm], b[fn], acc[fm][fn], 0, 0, 0);
    }
    __syncthreads();
  }
#pragma unroll
  for (int fm = 0; fm < 4; ++fm)
#pragma unroll
    for (int fn = 0; fn < 4; ++fn)
#pragma unroll
      for (int r = 0; r < 4; ++r)
        C[(size_t)(m0 + wm * 64 + fm * 16 + lk * 4 + r) * 1024 + n0 + wn * 64 + fn * 16 + lr] =
            acc[fm][fn][r];
}

extern "C" void kernel_launch(void* const* d_in, const int* in_sizes, int n_in,
                              void* d_out, int out_size, void* d_ws, size_t ws_size,
                              hipStream_t stream) {
  const float* x  = (const float*)d_in[0];
  const float* Wq = (const float*)d_in[1];
  const float* Wk = (const float*)d_in[2];
  const float* Wv = (const float*)d_in[3];
  const float* Wo = (const float*)d_in[4];
  const int* pos  = (const int*)d_in[5];
  float* out = (float*)d_out;
  char* ws = (char*)d_ws;

  // Workspace layout (bytes):
  unsigned short* xb  = (unsigned short*)(ws);              // 16 MB  x bf16 [8192][1024]
  unsigned short* Wb  = (unsigned short*)(ws + 16777216);   // 6 MB   Wq|Wk|Wv bf16 [3072][1024]
  unsigned short* Wob = (unsigned short*)(ws + 23068672);   // 2 MB   Wo bf16
  unsigned short* Qh  = (unsigned short*)(ws + 25165824);   // 16 MB  [B][H][S][64]
  unsigned short* Kh  = (unsigned short*)(ws + 41943040);   // 16 MB
  unsigned short* Ob  = (unsigned short*)(ws + 58720256);   // 16 MB  attn out bf16
  unsigned short* Vt  = (unsigned short*)(ws + 75497472);   // 16 MB  [B][H][64][S]
  float* tab          = (float*)(ws + 92274688);            // 512 KB cos/sin
  (void)in_sizes; (void)n_in; (void)out_size; (void)ws_size;

  k_prep<<<12544, 256, 0, stream>>>(x, Wq, Wk, Wv, Wo, pos, xb, Wb, Wob, tab);
  dim3 g1(64, 24);
  k_gemm_qkv<<<g1, 256, 0, stream>>>(xb, Wb, Qh, Kh, Vt, tab);
  dim3 ga(64, 8);
  k_attn<<<ga, 512, 0, stream>>>(Qh, Kh, Vt, Ob, tab);
  dim3 g2(64, 8);
  k_gemm_out<<<g2, 256, 0, stream>>>(Ob, Wob, out);
}